// Round 7
// baseline (161.502 us; speedup 1.0000x reference)
//
#include <hip/hip_runtime.h>
#include <math.h>

typedef __bf16 bf16;
typedef __bf16 bf16x4 __attribute__((ext_vector_type(4)));
typedef __bf16 bf16x8 __attribute__((ext_vector_type(8)));
typedef float  f32x4  __attribute__((ext_vector_type(4)));

#define BZd 16
#define INd 512
#define Sd  512
#define Od  512
#define Ld  2048

__device__ __forceinline__ int keyf(int r) { return (r & 3) ^ ((r >> 2) & 3); }

// ---- prep_all: 0-255 conv B, 256-511 conv C, 512-767 conv D (+dfa), 768 A_diag+flags
__global__ __launch_bounds__(256) void prep_all(const float* __restrict__ B,
                                                const float* __restrict__ C,
                                                const float* __restrict__ D,
                                                const float* __restrict__ Au,
                                                bf16* __restrict__ Bb, bf16* __restrict__ Cb,
                                                bf16* __restrict__ Db, float* __restrict__ A_diag,
                                                int* __restrict__ dfa, int* __restrict__ flags) {
    __shared__ int sred[4];
    int bid = blockIdx.x;
    if (bid == 768) {
        #pragma unroll
        for (int r = 0; r < 2; ++r) {
            int ss = threadIdx.x + r * 256;
            float x = Au[ss];
            float sp = fmaxf(x, 0.0f) + log1pf(expf(-fabsf(x)));
            A_diag[ss] = -sp;
        }
        flags[threadIdx.x] = 0;   // 256 lookback flags zeroed every call
        return;
    }
    int which = bid >> 8, lb = bid & 255;
    const float* src = which == 0 ? B : (which == 1 ? C : D);
    bf16* dst = which == 0 ? Bb : (which == 1 ? Cb : Db);
    int i = lb * 256 + threadIdx.x;
    f32x4 v = *(const f32x4*)&src[(size_t)i * 4];
    bf16x4 o = { (bf16)v[0], (bf16)v[1], (bf16)v[2], (bf16)v[3] };
    *(bf16x4*)&dst[(size_t)i * 4] = o;
    if (which == 2) {
        int nz = (v[0] != 0.f) | (v[1] != 0.f) | (v[2] != 0.f) | (v[3] != 0.f);
        unsigned long long bl = __ballot(nz);
        int wv = threadIdx.x >> 6;
        if ((threadIdx.x & 63) == 0) sred[wv] = (bl != 0ull);
        __syncthreads();
        if (threadIdx.x == 0) dfa[lb] = sred[0] | sred[1] | sred[2] | sred[3];
    }
}

// ---- unified 256x256 MFMA GEMM ----
// AREG=1 (gemm_bu): A staged from f32 u with in-register transpose; SCAN=1 fused scan epilogue.
// AREG=0 (gemm_y):  A,B via global_load_lds (bf16); optional cold D*u pass when dfa says D!=0.
template<int AREG, int SCAN>
__global__ __launch_bounds__(512, 2) void gemm8p(
    const bf16* __restrict__ Abf, size_t aBS,
    const float* __restrict__ Uf, size_t uBS,
    const bf16* __restrict__ Bbf, size_t bBS,
    const bf16* __restrict__ Dbf,
    const int* __restrict__ dfa,
    const float* __restrict__ A_diag,
    const float* __restrict__ h0,
    float* __restrict__ Lg, int* __restrict__ flags,
    void* __restrict__ OutV, size_t oBS, int ldOut,
    int NX, int NY)
{
    constexpr int RS   = AREG ? 40 : 32;        // A-region row stride (elems); 40 pads banks
    constexpr int ASZ  = 256 * RS;
    constexpr int SLOT = ASZ + 256 * 32;        // + B region (linear 64B rows, XOR-swizzled)
    __shared__ bf16 lds[4 * SLOT];

    const int tid = threadIdx.x;
    const int lane = tid & 63, w = tid >> 6;

    int nwg = gridDim.x, bid = blockIdx.x;
    int cpx = nwg >> 3;
    int swz = (bid & 7) * cpx + (bid >> 3);
    int pb = NX * NY;
    int b  = swz / pb;
    int r0 = swz - b * pb;
    int by = r0 / NX;
    int bx = r0 - by * NX;

    const int wm = w >> 2, wn = w & 3;
    const int fr = lane & 15, g = lane >> 4;
    const int iq = tid & 7, lq = tid >> 3;

    const bf16*  Ab = AREG ? nullptr : (Abf + (size_t)b * aBS + (size_t)(by * 256) * 512);
    const float* Ub = Uf ? (Uf + (size_t)b * uBS) : nullptr;
    const bf16*  Bp = Bbf + (size_t)b * bBS + (size_t)(bx * 256) * 512;

    int extra = 0;
    if (!AREG && dfa) {
        int4 f = ((const int4*)dfa)[lane];
        extra = __any((f.x | f.y | f.z | f.w) != 0) ? 1 : 0;
    }

    f32x4 acc[8][4];
    #pragma unroll
    for (int i = 0; i < 8; ++i)
        #pragma unroll
        for (int j = 0; j < 4; ++j)
            acc[i][j] = (f32x4){0.f, 0.f, 0.f, 0.f};

    f32x4 areg[4];

    #define GLD16(srcP, dstElem) __builtin_amdgcn_global_load_lds( \
        (const __attribute__((address_space(1))) void*)(srcP), \
        (__attribute__((address_space(3))) void*)&lds[dstElem], 16, 0, 0)

    auto gldA = [&](int U) {      // AGLD mode only
        #pragma unroll
        for (int rb = 0; rb < 2; ++rb) {
            int row = rb * 128 + (tid >> 2);
            int cs = (tid & 3) ^ keyf(row);
            GLD16(Ab + (size_t)row * 512 + U * 32 + cs * 8,
                  (U & 3) * SLOT + (rb * 128 + w * 16) * 32);
        }
    };
    auto gldB = [&](int U) {
        #pragma unroll
        for (int rb = 0; rb < 2; ++rb) {
            int row = rb * 128 + (tid >> 2);
            int cs = (tid & 3) ^ keyf(row);
            GLD16(Bp + (size_t)row * 512 + U * 32 + cs * 8,
                  (U & 3) * SLOT + ASZ + (rb * 128 + w * 16) * 32);
        }
    };
    auto issueA = [&](int U) {    // AREG: 4x f32x4 from u (k=i rows, contiguous in l)
        #pragma unroll
        for (int d = 0; d < 4; ++d)
            areg[d] = *(const f32x4*)&Ub[(size_t)(U * 32 + iq * 4 + d) * Ld + by * 256 + lq * 4];
    };
    auto writeA = [&](int U) {    // transpose 4i x 4l micro-block into padded A-region
        bf16* As = &lds[(U & 3) * SLOT];
        #pragma unroll
        for (int dl = 0; dl < 4; ++dl) {
            int r = lq * 4 + dl;
            bf16x4 wv = { (bf16)areg[0][dl], (bf16)areg[1][dl], (bf16)areg[2][dl], (bf16)areg[3][dl] };
            *(bf16x4*)&As[r * RS + iq * 4] = wv;
        }
    };
    auto readFrags = [&](int slot, bf16x8* avf, bf16x8* bvf) {
        const bf16* As = &lds[slot * SLOT];
        const bf16* Bs = &lds[slot * SLOT + ASZ];
        #pragma unroll
        for (int i = 0; i < 8; ++i) {
            int R = wm * 128 + i * 16 + fr;
            if (AREG) avf[i] = *(const bf16x8*)&As[R * RS + g * 8];
            else      avf[i] = *(const bf16x8*)&As[R * RS + (g ^ keyf(R)) * 8];
        }
        #pragma unroll
        for (int j = 0; j < 4; ++j) {
            int R = wn * 64 + j * 16 + fr;
            bvf[j] = *(const bf16x8*)&Bs[R * 32 + (g ^ keyf(R)) * 8];
        }
    };

    // ---- prologue ----
    if (AREG) { issueA(0); gldB(0); gldB(1); }
    else      { gldA(0); gldB(0); gldA(1); gldB(1); }

    // ---- hot loop: 16 units of BK=32 over K=512 ----
    for (int U = 0; U < 16; ++U) {
        if (U < 15) {
            if (AREG) asm volatile("s_waitcnt vmcnt(2)" ::: "memory");
            else      asm volatile("s_waitcnt vmcnt(4)" ::: "memory");
        } else {
            asm volatile("s_waitcnt vmcnt(0)" ::: "memory");
        }
        __builtin_amdgcn_sched_barrier(0);
        if (AREG) {
            writeA(U);
            asm volatile("s_waitcnt lgkmcnt(0)" ::: "memory");
        }
        __builtin_amdgcn_s_barrier();
        __builtin_amdgcn_sched_barrier(0);
        bf16x8 av[8], bv[4];
        readFrags(U & 3, av, bv);
        if (AREG) { if (U + 1 < 16) issueA(U + 1); }
        else      { if (U + 2 < 16) gldA(U + 2); }
        if (U + 2 < 16) gldB(U + 2);
        __builtin_amdgcn_s_setprio(1);
        #pragma unroll
        for (int i = 0; i < 8; ++i)
            #pragma unroll
            for (int j = 0; j < 4; ++j)
                acc[i][j] = __builtin_amdgcn_mfma_f32_16x16x32_bf16(av[i], bv[j], acc[i][j], 0, 0, 0);
        __builtin_amdgcn_s_setprio(0);
    }

    // ---- cold pass (gemm_y, D != 0 only; correctness path, not perf) ----
    if (!AREG) {
        if (extra) {
            #pragma unroll 1
            for (int T = 0; T < 16; ++T) {
                int k0 = T * 32;
                __builtin_amdgcn_s_barrier();   // everyone done reading slot0 from prev iter
                f32x4 r4[4];
                #pragma unroll
                for (int d = 0; d < 4; ++d)
                    r4[d] = *(const f32x4*)&Ub[(size_t)(k0 + iq * 4 + d) * Ld + bx * 256 + lq * 4];
                #pragma unroll
                for (int rb = 0; rb < 2; ++rb) {
                    int row = rb * 128 + (tid >> 2);
                    int cs = (tid & 3) ^ keyf(row);
                    GLD16(Dbf + (size_t)(by * 256 + row) * 512 + k0 + cs * 8,
                          (rb * 128 + w * 16) * 32);
                }
                asm volatile("s_waitcnt vmcnt(0)" ::: "memory");
                #pragma unroll
                for (int dl = 0; dl < 4; ++dl) {
                    int r = lq * 4 + dl;
                    bf16x4 wv = { (bf16)r4[0][dl], (bf16)r4[1][dl], (bf16)r4[2][dl], (bf16)r4[3][dl] };
                    int e = ((iq >> 1) ^ keyf(r)) * 8 + (iq & 1) * 4;
                    *(bf16x4*)&lds[ASZ + r * 32 + e] = wv;
                }
                asm volatile("s_waitcnt lgkmcnt(0)" ::: "memory");
                __builtin_amdgcn_s_barrier();
                bf16x8 av[8], bv[4];
                readFrags(0, av, bv);
                #pragma unroll
                for (int i = 0; i < 8; ++i)
                    #pragma unroll
                    for (int j = 0; j < 4; ++j)
                        acc[i][j] = __builtin_amdgcn_mfma_f32_16x16x32_bf16(av[i], bv[j], acc[i][j], 0, 0, 0);
            }
        }
    }

    int n0 = bx * 256 + wn * 64 + fr;
    int m0 = by * 256 + wm * 128 + g * 4;

    // ---- fused scan epilogue (gemm_bu) ----
    if (SCAN) {
        float av_[4], a2_[4], a4_[4], a16_[4], a128_[4], a256_[4], A4G_[4];
        #pragma unroll
        for (int j = 0; j < 4; ++j) {
            float a = A_diag[n0 + j * 16];
            float a2 = a * a, a4 = a2 * a2, a8 = a4 * a4, a16 = a8 * a8;
            float a32 = a16 * a16, a64 = a32 * a32, a128 = a64 * a64;
            av_[j] = a; a2_[j] = a2; a4_[j] = a4; a16_[j] = a16;
            a128_[j] = a128; a256_[j] = a128 * a128;
            A4G_[j] = (g == 0) ? 1.0f : (g == 1) ? a4 : (g == 2) ? a8 : a8 * a4;
        }
        // pass 1: zero-init local scan over this wave's 128 rows, in place in acc
        float P8[4];
        #pragma unroll
        for (int j = 0; j < 4; ++j) {
            float a = av_[j], a4 = a4_[j], a16 = a16_[j];
            float P = 0.0f;
            #pragma unroll
            for (int i = 0; i < 8; ++i) {
                f32x4 v = acc[i][j];
                float e = fmaf(fmaf(fmaf(v[0], a, v[1]), a, v[2]), a, v[3]);
                float e0 = __shfl(e, fr), e1 = __shfl(e, fr + 16);
                float e2 = __shfl(e, fr + 32), e3 = __shfl(e, fr + 48);
                float E = fmaf(fmaf(fmaf(e0, a4, e1), a4, e2), a4, e3);
                float h2 = fmaf(e0, a4, e1), h3 = fmaf(h2, a4, e2);
                float PG = (g == 0) ? 0.0f : (g == 1) ? e0 : (g == 2) ? h2 : h3;
                float Vg = fmaf(A4G_[j], P, PG);
                float x0 = fmaf(a, Vg, v[0]);
                float x1 = fmaf(a, x0, v[1]);
                float x2 = fmaf(a, x1, v[2]);
                float x3 = fmaf(a, x2, v[3]);
                acc[i][j] = (f32x4){x0, x1, x2, x3};
                P = fmaf(P, a16, E);
            }
            P8[j] = P;
        }
        // cross-wave (wm0 -> wm1) via LDS scratch
        float* sc = (float*)lds;
        __syncthreads();
        if (wm == 0 && g == 0) {
            #pragma unroll
            for (int j = 0; j < 4; ++j) sc[wn * 64 + j * 16 + fr] = P8[j];
        }
        __syncthreads();
        float L0[4] = {0.f, 0.f, 0.f, 0.f};
        if (wm == 1) {
            #pragma unroll
            for (int j = 0; j < 4; ++j) L0[j] = sc[wn * 64 + j * 16 + fr];
        }
        // publish local 256-row end L (independent of predecessors)
        int fbase = (b * NX + bx) * 8;
        size_t lbase = ((size_t)(fbase + by)) * 256;
        if (wm == 1 && g == 0) {
            #pragma unroll
            for (int j = 0; j < 4; ++j)
                __hip_atomic_store(&Lg[lbase + wn * 64 + j * 16 + fr],
                                   fmaf(L0[j], a128_[j], P8[j]),
                                   __ATOMIC_RELAXED, __HIP_MEMORY_SCOPE_AGENT);
        }
        __syncthreads();
        __threadfence();
        if (tid == 0)
            __hip_atomic_store(&flags[fbase + by], 1, __ATOMIC_RELEASE, __HIP_MEMORY_SCOPE_AGENT);
        // lookback: combine predecessors (all co-resident; grid == CU count)
        float W[4];
        #pragma unroll
        for (int j = 0; j < 4; ++j) W[j] = h0[n0 + j * 16];
        for (int k = 0; k < by; ++k) {
            while (__hip_atomic_load(&flags[fbase + k], __ATOMIC_ACQUIRE, __HIP_MEMORY_SCOPE_AGENT) == 0)
                __builtin_amdgcn_s_sleep(2);
            size_t lk = ((size_t)(fbase + k)) * 256;
            #pragma unroll
            for (int j = 0; j < 4; ++j) {
                float Lk = __hip_atomic_load(&Lg[lk + wn * 64 + j * 16 + fr],
                                             __ATOMIC_RELAXED, __HIP_MEMORY_SCOPE_AGENT);
                W[j] = fmaf(W[j], a256_[j], Lk);
            }
        }
        // pass 2: add a^(r+1) * W
        #pragma unroll
        for (int j = 0; j < 4; ++j) {
            float Wh = (wm == 0) ? W[j] : fmaf(W[j], a128_[j], L0[j]);
            float a = av_[j], a2 = a2_[j], a3 = a2 * a, a4 = a4_[j];
            float pw = A4G_[j] * Wh;
            #pragma unroll
            for (int i = 0; i < 8; ++i) {
                f32x4 x = acc[i][j];
                x[0] = fmaf(pw, a,  x[0]);
                x[1] = fmaf(pw, a2, x[1]);
                x[2] = fmaf(pw, a3, x[2]);
                x[3] = fmaf(pw, a4, x[3]);
                acc[i][j] = x;
                pw *= a16_[j];
            }
        }
    }

    // ---- store: C/D layout col=lane&15, row=(lane>>4)*4+reg ----
    if (SCAN) {
        bf16* out = (bf16*)OutV + (size_t)b * oBS;
        #pragma unroll
        for (int i = 0; i < 8; ++i)
            #pragma unroll
            for (int j = 0; j < 4; ++j)
                #pragma unroll
                for (int q = 0; q < 4; ++q)
                    out[(size_t)(m0 + i * 16 + q) * ldOut + n0 + j * 16] = (bf16)acc[i][j][q];
    } else {
        float* out = (float*)OutV + (size_t)b * oBS;
        #pragma unroll
        for (int i = 0; i < 8; ++i)
            #pragma unroll
            for (int j = 0; j < 4; ++j)
                #pragma unroll
                for (int q = 0; q < 4; ++q)
                    out[(size_t)(m0 + i * 16 + q) * ldOut + n0 + j * 16] = acc[i][j][q];
    }
    #undef GLD16
}

extern "C" void kernel_launch(void* const* d_in, const int* in_sizes, int n_in,
                              void* d_out, int out_size, void* d_ws, size_t ws_size,
                              hipStream_t stream) {
    const float* u  = (const float*)d_in[0];
    const float* Au = (const float*)d_in[1];
    const float* Bm = (const float*)d_in[2];
    const float* Cm = (const float*)d_in[3];
    const float* Dm = (const float*)d_in[4];
    const float* h0 = (const float*)d_in[5];
    float* Y = (float*)d_out;

    char* ws = (char*)d_ws;
    bf16* xs = (bf16*)ws;                              // 32 MiB: Bu -> scanned xs (bf16)
    bf16* Bb = (bf16*)(ws + (32ull << 20));            // 512 KiB each
    bf16* Cb = Bb + 262144;
    bf16* Db = Cb + 262144;
    float* A_diag = (float*)(ws + (32ull << 20) + 3ull * 524288);   // 2 KiB
    float* Lg     = A_diag + 512;                      // 16*2*8*256 f32 = 256 KiB
    int*   flags  = (int*)(Lg + 16 * 2 * 8 * 256);     // 256 ints
    int*   dfa    = flags + 256;                       // 256 ints

    prep_all<<<769, 256, 0, stream>>>(Bm, Cm, Dm, Au, Bb, Cb, Db, A_diag, dfa, flags);

    // gemm_bu + fused scan: M=l(2048) via by, N=s(512) via bx; A from u (reg-transpose), B=Bb
    gemm8p<1, 1><<<(Sd / 256) * (Ld / 256) * BZd, 512, 0, stream>>>(
        nullptr, 0, u, (size_t)INd * Ld, Bb, 0, nullptr,
        nullptr, A_diag, h0, Lg, flags,
        (void*)xs, (size_t)Ld * Sd, Sd,
        Sd / 256, Ld / 256);

    // gemm_y: M=o(512) via by, N=l(2048) via bx; A=Cb, B=xs; cold D*u pass iff D!=0
    gemm8p<0, 0><<<(Ld / 256) * (Od / 256) * BZd, 512, 0, stream>>>(
        Cb, 0, u, (size_t)INd * Ld, xs, (size_t)Ld * Sd, Db,
        dfa, A_diag, h0, nullptr, nullptr,
        (void*)Y, (size_t)Od * Ld, Ld,
        Ld / 256, Od / 256);
}

// Round 8
// 160.294 us; speedup vs baseline: 1.0075x; 1.0075x over previous
//
#include <hip/hip_runtime.h>
#include <math.h>

typedef __bf16 bf16;
typedef __bf16 bf16x4 __attribute__((ext_vector_type(4)));
typedef __bf16 bf16x8 __attribute__((ext_vector_type(8)));
typedef float  f32x4  __attribute__((ext_vector_type(4)));

#define BZd 16
#define INd 512
#define Sd  512
#define Od  512
#define Ld  2048

__device__ __forceinline__ int keyf(int r) { return (r & 3) ^ ((r >> 2) & 3); }

// ---- prep_all: 0-255 conv B, 256-511 conv C, 512-767 conv D (+dfa), 768 A_diag+flags
__global__ __launch_bounds__(256) void prep_all(const float* __restrict__ B,
                                                const float* __restrict__ C,
                                                const float* __restrict__ D,
                                                const float* __restrict__ Au,
                                                bf16* __restrict__ Bb, bf16* __restrict__ Cb,
                                                bf16* __restrict__ Db, float* __restrict__ A_diag,
                                                int* __restrict__ dfa, int* __restrict__ flags) {
    __shared__ int sred[4];
    int bid = blockIdx.x;
    if (bid == 768) {
        #pragma unroll
        for (int r = 0; r < 2; ++r) {
            int ss = threadIdx.x + r * 256;
            float x = Au[ss];
            float sp = fmaxf(x, 0.0f) + log1pf(expf(-fabsf(x)));
            A_diag[ss] = -sp;
        }
        flags[threadIdx.x] = 0;   // 256 lookback flags zeroed every call
        return;
    }
    int which = bid >> 8, lb = bid & 255;
    const float* src = which == 0 ? B : (which == 1 ? C : D);
    bf16* dst = which == 0 ? Bb : (which == 1 ? Cb : Db);
    int i = lb * 256 + threadIdx.x;
    f32x4 v = *(const f32x4*)&src[(size_t)i * 4];
    bf16x4 o = { (bf16)v[0], (bf16)v[1], (bf16)v[2], (bf16)v[3] };
    *(bf16x4*)&dst[(size_t)i * 4] = o;
    if (which == 2) {
        int nz = (v[0] != 0.f) | (v[1] != 0.f) | (v[2] != 0.f) | (v[3] != 0.f);
        unsigned long long bl = __ballot(nz);
        int wv = threadIdx.x >> 6;
        if ((threadIdx.x & 63) == 0) sred[wv] = (bl != 0ull);
        __syncthreads();
        if (threadIdx.x == 0) dfa[lb] = sred[0] | sred[1] | sred[2] | sred[3];
    }
}

// ---- unified 256x256 MFMA GEMM ----
// AREG=1 (gemm_bu): A staged from f32 u with in-register transpose; SCAN=1 fused scan epilogue.
// AREG=0 (gemm_y):  A,B via global_load_lds (bf16); optional cold D*u pass when dfa says D!=0.
template<int AREG, int SCAN>
__global__ __launch_bounds__(512, 2) void gemm8p(
    const bf16* __restrict__ Abf, size_t aBS,
    const float* __restrict__ Uf, size_t uBS,
    const bf16* __restrict__ Bbf, size_t bBS,
    const bf16* __restrict__ Dbf,
    const int* __restrict__ dfa,
    const float* __restrict__ A_diag,
    const float* __restrict__ h0,
    float* __restrict__ Lg, int* __restrict__ flags,
    void* __restrict__ OutV, size_t oBS, int ldOut,
    int NX, int NY)
{
    constexpr int RS   = AREG ? 40 : 32;        // A-region row stride (elems); 40 pads banks
    constexpr int ASZ  = 256 * RS;
    constexpr int SLOT = ASZ + 256 * 32;        // + B region (linear 64B rows, XOR-swizzled)
    __shared__ bf16 lds[4 * SLOT];

    const int tid = threadIdx.x;
    const int lane = tid & 63, w = tid >> 6;

    int nwg = gridDim.x, bid = blockIdx.x;
    int cpx = nwg >> 3;
    int swz = (bid & 7) * cpx + (bid >> 3);
    int pb = NX * NY;
    int b  = swz / pb;
    int r0 = swz - b * pb;
    int by = r0 / NX;
    int bx = r0 - by * NX;

    const int wm = w >> 2, wn = w & 3;
    const int fr = lane & 15, g = lane >> 4;
    const int iq = tid & 7, lq = tid >> 3;

    const bf16*  Ab = AREG ? nullptr : (Abf + (size_t)b * aBS + (size_t)(by * 256) * 512);
    const float* Ub = Uf ? (Uf + (size_t)b * uBS) : nullptr;
    const bf16*  Bp = Bbf + (size_t)b * bBS + (size_t)(bx * 256) * 512;

    int extra = 0;
    if (!AREG && dfa) {
        int4 f = ((const int4*)dfa)[lane];
        extra = __any((f.x | f.y | f.z | f.w) != 0) ? 1 : 0;
    }

    f32x4 acc[8][4];
    #pragma unroll
    for (int i = 0; i < 8; ++i)
        #pragma unroll
        for (int j = 0; j < 4; ++j)
            acc[i][j] = (f32x4){0.f, 0.f, 0.f, 0.f};

    f32x4 areg[4];

    #define GLD16(srcP, dstElem) __builtin_amdgcn_global_load_lds( \
        (const __attribute__((address_space(1))) void*)(srcP), \
        (__attribute__((address_space(3))) void*)&lds[dstElem], 16, 0, 0)

    auto gldA = [&](int U) {      // AGLD mode only
        #pragma unroll
        for (int rb = 0; rb < 2; ++rb) {
            int row = rb * 128 + (tid >> 2);
            int cs = (tid & 3) ^ keyf(row);
            GLD16(Ab + (size_t)row * 512 + U * 32 + cs * 8,
                  (U & 3) * SLOT + (rb * 128 + w * 16) * 32);
        }
    };
    auto gldB = [&](int U) {
        #pragma unroll
        for (int rb = 0; rb < 2; ++rb) {
            int row = rb * 128 + (tid >> 2);
            int cs = (tid & 3) ^ keyf(row);
            GLD16(Bp + (size_t)row * 512 + U * 32 + cs * 8,
                  (U & 3) * SLOT + ASZ + (rb * 128 + w * 16) * 32);
        }
    };
    auto issueA = [&](int U) {    // AREG: 4x f32x4 from u (k=i rows, contiguous in l)
        #pragma unroll
        for (int d = 0; d < 4; ++d)
            areg[d] = *(const f32x4*)&Ub[(size_t)(U * 32 + iq * 4 + d) * Ld + by * 256 + lq * 4];
    };
    auto writeA = [&](int U) {    // transpose 4i x 4l micro-block into padded A-region
        bf16* As = &lds[(U & 3) * SLOT];
        #pragma unroll
        for (int dl = 0; dl < 4; ++dl) {
            int r = lq * 4 + dl;
            bf16x4 wv = { (bf16)areg[0][dl], (bf16)areg[1][dl], (bf16)areg[2][dl], (bf16)areg[3][dl] };
            *(bf16x4*)&As[r * RS + iq * 4] = wv;
        }
    };
    auto readFrags = [&](int slot, bf16x8* avf, bf16x8* bvf) {
        const bf16* As = &lds[slot * SLOT];
        const bf16* Bs = &lds[slot * SLOT + ASZ];
        #pragma unroll
        for (int i = 0; i < 8; ++i) {
            int R = wm * 128 + i * 16 + fr;
            if (AREG) avf[i] = *(const bf16x8*)&As[R * RS + g * 8];
            else      avf[i] = *(const bf16x8*)&As[R * RS + (g ^ keyf(R)) * 8];
        }
        #pragma unroll
        for (int j = 0; j < 4; ++j) {
            int R = wn * 64 + j * 16 + fr;
            bvf[j] = *(const bf16x8*)&Bs[R * 32 + (g ^ keyf(R)) * 8];
        }
    };

    // ---- prologue ----
    if (AREG) { issueA(0); gldB(0); gldB(1); }
    else      { gldA(0); gldB(0); gldA(1); gldB(1); }

    // ---- hot loop: 16 units of BK=32 over K=512 ----
    for (int U = 0; U < 16; ++U) {
        if (U < 15) {
            if (AREG) asm volatile("s_waitcnt vmcnt(2)" ::: "memory");
            else      asm volatile("s_waitcnt vmcnt(4)" ::: "memory");
        } else {
            asm volatile("s_waitcnt vmcnt(0)" ::: "memory");
        }
        __builtin_amdgcn_sched_barrier(0);
        if (AREG) {
            writeA(U);
            asm volatile("s_waitcnt lgkmcnt(0)" ::: "memory");
        }
        __builtin_amdgcn_s_barrier();
        __builtin_amdgcn_sched_barrier(0);
        bf16x8 av[8], bv[4];
        readFrags(U & 3, av, bv);
        if (AREG) { if (U + 1 < 16) issueA(U + 1); }
        else      { if (U + 2 < 16) gldA(U + 2); }
        if (U + 2 < 16) gldB(U + 2);
        __builtin_amdgcn_s_setprio(1);
        #pragma unroll
        for (int i = 0; i < 8; ++i)
            #pragma unroll
            for (int j = 0; j < 4; ++j)
                acc[i][j] = __builtin_amdgcn_mfma_f32_16x16x32_bf16(av[i], bv[j], acc[i][j], 0, 0, 0);
        __builtin_amdgcn_s_setprio(0);
    }

    // ---- cold pass (gemm_y, D != 0 only; correctness path, not perf) ----
    if (!AREG) {
        if (extra) {
            #pragma unroll 1
            for (int T = 0; T < 16; ++T) {
                int k0 = T * 32;
                __builtin_amdgcn_s_barrier();   // everyone done reading slot0 from prev iter
                f32x4 r4[4];
                #pragma unroll
                for (int d = 0; d < 4; ++d)
                    r4[d] = *(const f32x4*)&Ub[(size_t)(k0 + iq * 4 + d) * Ld + bx * 256 + lq * 4];
                #pragma unroll
                for (int rb = 0; rb < 2; ++rb) {
                    int row = rb * 128 + (tid >> 2);
                    int cs = (tid & 3) ^ keyf(row);
                    GLD16(Dbf + (size_t)(by * 256 + row) * 512 + k0 + cs * 8,
                          (rb * 128 + w * 16) * 32);
                }
                asm volatile("s_waitcnt vmcnt(0)" ::: "memory");
                #pragma unroll
                for (int dl = 0; dl < 4; ++dl) {
                    int r = lq * 4 + dl;
                    bf16x4 wv = { (bf16)r4[0][dl], (bf16)r4[1][dl], (bf16)r4[2][dl], (bf16)r4[3][dl] };
                    int e = ((iq >> 1) ^ keyf(r)) * 8 + (iq & 1) * 4;
                    *(bf16x4*)&lds[ASZ + r * 32 + e] = wv;
                }
                asm volatile("s_waitcnt lgkmcnt(0)" ::: "memory");
                __builtin_amdgcn_s_barrier();
                bf16x8 av[8], bv[4];
                readFrags(0, av, bv);
                #pragma unroll
                for (int i = 0; i < 8; ++i)
                    #pragma unroll
                    for (int j = 0; j < 4; ++j)
                        acc[i][j] = __builtin_amdgcn_mfma_f32_16x16x32_bf16(av[i], bv[j], acc[i][j], 0, 0, 0);
            }
        }
    }

    int n0 = bx * 256 + wn * 64 + fr;
    int m0 = by * 256 + wm * 128 + g * 4;

    // ---- fused scan epilogue (gemm_bu) ----
    if (SCAN) {
        float av_[4], a2_[4], a4_[4], a16_[4], a128_[4], a256_[4], A4G_[4];
        #pragma unroll
        for (int j = 0; j < 4; ++j) {
            float a = A_diag[n0 + j * 16];
            float a2 = a * a, a4 = a2 * a2, a8 = a4 * a4, a16 = a8 * a8;
            float a32 = a16 * a16, a64 = a32 * a32, a128 = a64 * a64;
            av_[j] = a; a2_[j] = a2; a4_[j] = a4; a16_[j] = a16;
            a128_[j] = a128; a256_[j] = a128 * a128;
            A4G_[j] = (g == 0) ? 1.0f : (g == 1) ? a4 : (g == 2) ? a8 : a8 * a4;
        }
        // pass 1: zero-init local scan over this wave's 128 rows, in place in acc
        float P8[4];
        #pragma unroll
        for (int j = 0; j < 4; ++j) {
            float a = av_[j], a4 = a4_[j], a16 = a16_[j];
            float P = 0.0f;
            #pragma unroll
            for (int i = 0; i < 8; ++i) {
                f32x4 v = acc[i][j];
                float e = fmaf(fmaf(fmaf(v[0], a, v[1]), a, v[2]), a, v[3]);
                float e0 = __shfl(e, fr), e1 = __shfl(e, fr + 16);
                float e2 = __shfl(e, fr + 32), e3 = __shfl(e, fr + 48);
                float E = fmaf(fmaf(fmaf(e0, a4, e1), a4, e2), a4, e3);
                float h2 = fmaf(e0, a4, e1), h3 = fmaf(h2, a4, e2);
                float PG = (g == 0) ? 0.0f : (g == 1) ? e0 : (g == 2) ? h2 : h3;
                float Vg = fmaf(A4G_[j], P, PG);
                float x0 = fmaf(a, Vg, v[0]);
                float x1 = fmaf(a, x0, v[1]);
                float x2 = fmaf(a, x1, v[2]);
                float x3 = fmaf(a, x2, v[3]);
                acc[i][j] = (f32x4){x0, x1, x2, x3};
                P = fmaf(P, a16, E);
            }
            P8[j] = P;
        }
        // cross-wave (wm0 -> wm1) via LDS scratch
        float* sc = (float*)lds;
        __syncthreads();
        if (wm == 0 && g == 0) {
            #pragma unroll
            for (int j = 0; j < 4; ++j) sc[wn * 64 + j * 16 + fr] = P8[j];
        }
        __syncthreads();
        float L0[4] = {0.f, 0.f, 0.f, 0.f};
        if (wm == 1) {
            #pragma unroll
            for (int j = 0; j < 4; ++j) L0[j] = sc[wn * 64 + j * 16 + fr];
        }
        // publish local 256-row end L (independent of predecessors)
        int fbase = (b * NX + bx) * 8;
        size_t lbase = ((size_t)(fbase + by)) * 256;
        if (wm == 1 && g == 0) {
            #pragma unroll
            for (int j = 0; j < 4; ++j)
                __hip_atomic_store(&Lg[lbase + wn * 64 + j * 16 + fr],
                                   fmaf(L0[j], a128_[j], P8[j]),
                                   __ATOMIC_RELAXED, __HIP_MEMORY_SCOPE_AGENT);
        }
        __syncthreads();
        __threadfence();
        if (tid == 0)
            __hip_atomic_store(&flags[fbase + by], 1, __ATOMIC_RELEASE, __HIP_MEMORY_SCOPE_AGENT);
        // lookback: combine predecessors (all co-resident; grid == CU count)
        float W[4];
        #pragma unroll
        for (int j = 0; j < 4; ++j) W[j] = h0[n0 + j * 16];
        for (int k = 0; k < by; ++k) {
            while (__hip_atomic_load(&flags[fbase + k], __ATOMIC_ACQUIRE, __HIP_MEMORY_SCOPE_AGENT) == 0)
                __builtin_amdgcn_s_sleep(2);
            size_t lk = ((size_t)(fbase + k)) * 256;
            #pragma unroll
            for (int j = 0; j < 4; ++j) {
                float Lk = __hip_atomic_load(&Lg[lk + wn * 64 + j * 16 + fr],
                                             __ATOMIC_RELAXED, __HIP_MEMORY_SCOPE_AGENT);
                W[j] = fmaf(W[j], a256_[j], Lk);
            }
        }
        // pass 2: add a^(r+1) * W
        #pragma unroll
        for (int j = 0; j < 4; ++j) {
            float Wh = (wm == 0) ? W[j] : fmaf(W[j], a128_[j], L0[j]);
            float a = av_[j], a2 = a2_[j], a3 = a2 * a, a4 = a4_[j];
            float pw = A4G_[j] * Wh;
            #pragma unroll
            for (int i = 0; i < 8; ++i) {
                f32x4 x = acc[i][j];
                x[0] = fmaf(pw, a,  x[0]);
                x[1] = fmaf(pw, a2, x[1]);
                x[2] = fmaf(pw, a3, x[2]);
                x[3] = fmaf(pw, a4, x[3]);
                acc[i][j] = x;
                pw *= a16_[j];
            }
        }
    }

    // ---- store: C/D layout col=lane&15, row=(lane>>4)*4+reg ----
    if (SCAN) {
        bf16* out = (bf16*)OutV + (size_t)b * oBS;
        #pragma unroll
        for (int i = 0; i < 8; ++i)
            #pragma unroll
            for (int j = 0; j < 4; ++j)
                #pragma unroll
                for (int q = 0; q < 4; ++q)
                    out[(size_t)(m0 + i * 16 + q) * ldOut + n0 + j * 16] = (bf16)acc[i][j][q];
    } else {
        float* out = (float*)OutV + (size_t)b * oBS;
        #pragma unroll
        for (int i = 0; i < 8; ++i)
            #pragma unroll
            for (int j = 0; j < 4; ++j)
                #pragma unroll
                for (int q = 0; q < 4; ++q)
                    out[(size_t)(m0 + i * 16 + q) * ldOut + n0 + j * 16] = acc[i][j][q];
    }
    #undef GLD16
}

extern "C" void kernel_launch(void* const* d_in, const int* in_sizes, int n_in,
                              void* d_out, int out_size, void* d_ws, size_t ws_size,
                              hipStream_t stream) {
    const float* u  = (const float*)d_in[0];
    const float* Au = (const float*)d_in[1];
    const float* Bm = (const float*)d_in[2];
    const float* Cm = (const float*)d_in[3];
    const float* Dm = (const float*)d_in[4];
    const float* h0 = (const float*)d_in[5];
    float* Y = (float*)d_out;

    char* ws = (char*)d_ws;
    bf16* xs = (bf16*)ws;                              // 32 MiB: Bu -> scanned xs (bf16)
    bf16* Bb = (bf16*)(ws + (32ull << 20));            // 512 KiB each
    bf16* Cb = Bb + 262144;
    bf16* Db = Cb + 262144;
    float* A_diag = (float*)(ws + (32ull << 20) + 3ull * 524288);   // 2 KiB
    float* Lg     = A_diag + 512;                      // 16*2*8*256 f32 = 256 KiB
    int*   flags  = (int*)(Lg + 16 * 2 * 8 * 256);     // 256 ints
    int*   dfa    = flags + 256;                       // 256 ints

    prep_all<<<769, 256, 0, stream>>>(Bm, Cm, Dm, Au, Bb, Cb, Db, A_diag, dfa, flags);

    // gemm_bu + fused scan: M=l(2048) via by, N=s(512) via bx; A from u (reg-transpose), B=Bb
    gemm8p<1, 1><<<(Sd / 256) * (Ld / 256) * BZd, 512, 0, stream>>>(
        nullptr, 0, u, (size_t)INd * Ld, Bb, 0, nullptr,
        nullptr, A_diag, h0, Lg, flags,
        (void*)xs, (size_t)Ld * Sd, Sd,
        Sd / 256, Ld / 256);

    // gemm_y: M=o(512) via by, N=l(2048) via bx; A=Cb, B=xs; cold D*u pass iff D!=0
    gemm8p<0, 0><<<(Ld / 256) * (Od / 256) * BZd, 512, 0, stream>>>(
        Cb, 0, u, (size_t)INd * Ld, xs, (size_t)Ld * Sd, Db,
        dfa, A_diag, h0, nullptr, nullptr,
        (void*)Y, (size_t)Od * Ld, Ld,
        Ld / 256, Od / 256);
}

// Round 9
// 87.399 us; speedup vs baseline: 1.8479x; 1.8340x over previous
//
#include <hip/hip_runtime.h>
#include <math.h>

typedef __bf16 bf16;
typedef __bf16 bf16x2 __attribute__((ext_vector_type(2)));
typedef __bf16 bf16x4 __attribute__((ext_vector_type(4)));
typedef __bf16 bf16x8 __attribute__((ext_vector_type(8)));
typedef float  f32x4  __attribute__((ext_vector_type(4)));

#define BZd 16
#define INd 512
#define Sd  512
#define Od  512
#define Ld  2048
#define CLd 128
#define NCd (Ld / CLd)   // 16 chunks of 128

__device__ __forceinline__ int keyf(int r) { return (r & 3) ^ ((r >> 2) & 3); }

// ---- prep_all: 0-255 conv B, 256-511 conv C, 512-767 conv D (+dfa), 768 A_diag
__global__ __launch_bounds__(256) void prep_all(const float* __restrict__ B,
                                                const float* __restrict__ C,
                                                const float* __restrict__ D,
                                                const float* __restrict__ Au,
                                                bf16* __restrict__ Bb, bf16* __restrict__ Cb,
                                                bf16* __restrict__ Db, float* __restrict__ A_diag,
                                                int* __restrict__ dfa) {
    __shared__ int sred[4];
    int bid = blockIdx.x;
    if (bid == 768) {
        #pragma unroll
        for (int r = 0; r < 2; ++r) {
            int ss = threadIdx.x + r * 256;
            float x = Au[ss];
            float sp = fmaxf(x, 0.0f) + log1pf(expf(-fabsf(x)));
            A_diag[ss] = -sp;
        }
        return;
    }
    int which = bid >> 8, lb = bid & 255;
    const float* src = which == 0 ? B : (which == 1 ? C : D);
    bf16* dst = which == 0 ? Bb : (which == 1 ? Cb : Db);
    int i = lb * 256 + threadIdx.x;
    f32x4 v = *(const f32x4*)&src[(size_t)i * 4];
    bf16x4 o = { (bf16)v[0], (bf16)v[1], (bf16)v[2], (bf16)v[3] };
    *(bf16x4*)&dst[(size_t)i * 4] = o;
    if (which == 2) {
        int nz = (v[0] != 0.f) | (v[1] != 0.f) | (v[2] != 0.f) | (v[3] != 0.f);
        unsigned long long bl = __ballot(nz);
        int wv = threadIdx.x >> 6;
        if ((threadIdx.x & 63) == 0) sred[wv] = (bl != 0ull);
        __syncthreads();
        if (threadIdx.x == 0) dfa[lb] = sred[0] | sred[1] | sred[2] | sred[3];
    }
}

// ---- unified 256x256 MFMA GEMM, BK=32 units, counted-vmcnt pipeline ----
// AREG=1 (gemm_bu): A staged from f32 u with in-register transpose (padded LDS rows).
// SCAN=1: epilogue computes per-128-row-chunk zero-init scan ends into cePtr.
// AREG=0 (gemm_y): A,B via global_load_lds; cold D*u pass when dfa says D!=0.
template<int AREG, int SCAN>
__global__ __launch_bounds__(512, 2) void gemm8p(
    const bf16* __restrict__ Abf, size_t aBS,
    const float* __restrict__ Uf, size_t uBS,
    const bf16* __restrict__ Bbf, size_t bBS,
    const bf16* __restrict__ Dbf,
    const int* __restrict__ dfa,
    const float* __restrict__ A_diag, float* __restrict__ cePtr,
    void* __restrict__ OutV, size_t oBS, int ldOut,
    int NX, int NY)
{
    constexpr int RS   = AREG ? 40 : 32;        // A-region row stride (elems); 40 pads banks
    constexpr int ASZ  = 256 * RS;
    constexpr int SLOT = ASZ + 256 * 32;        // + B region (linear 64B rows, XOR-swizzled)
    __shared__ bf16 lds[4 * SLOT];

    const int tid = threadIdx.x;
    const int lane = tid & 63, w = tid >> 6;

    int nwg = gridDim.x, bid = blockIdx.x;
    int cpx = nwg >> 3;
    int swz = (bid & 7) * cpx + (bid >> 3);
    int pb = NX * NY;
    int b  = swz / pb;
    int r0 = swz - b * pb;
    int by = r0 / NX;
    int bx = r0 - by * NX;

    const int wm = w >> 2, wn = w & 3;
    const int fr = lane & 15, g = lane >> 4;
    const int iq = tid & 7, lq = tid >> 3;

    const bf16*  Ab = AREG ? nullptr : (Abf + (size_t)b * aBS + (size_t)(by * 256) * 512);
    const float* Ub = Uf ? (Uf + (size_t)b * uBS) : nullptr;
    const bf16*  Bp = Bbf + (size_t)b * bBS + (size_t)(bx * 256) * 512;

    int extra = 0;
    if (!AREG && dfa) {
        int4 f = ((const int4*)dfa)[lane];
        extra = __any((f.x | f.y | f.z | f.w) != 0) ? 1 : 0;
    }

    f32x4 acc[8][4];
    #pragma unroll
    for (int i = 0; i < 8; ++i)
        #pragma unroll
        for (int j = 0; j < 4; ++j)
            acc[i][j] = (f32x4){0.f, 0.f, 0.f, 0.f};

    f32x4 areg[4];

    #define GLD16(srcP, dstElem) __builtin_amdgcn_global_load_lds( \
        (const __attribute__((address_space(1))) void*)(srcP), \
        (__attribute__((address_space(3))) void*)&lds[dstElem], 16, 0, 0)

    auto gldA = [&](int U) {      // AREG=0 only
        #pragma unroll
        for (int rb = 0; rb < 2; ++rb) {
            int row = rb * 128 + (tid >> 2);
            int cs = (tid & 3) ^ keyf(row);
            GLD16(Ab + (size_t)row * 512 + U * 32 + cs * 8,
                  (U & 3) * SLOT + (rb * 128 + w * 16) * 32);
        }
    };
    auto gldB = [&](int U) {
        #pragma unroll
        for (int rb = 0; rb < 2; ++rb) {
            int row = rb * 128 + (tid >> 2);
            int cs = (tid & 3) ^ keyf(row);
            GLD16(Bp + (size_t)row * 512 + U * 32 + cs * 8,
                  (U & 3) * SLOT + ASZ + (rb * 128 + w * 16) * 32);
        }
    };
    auto issueA = [&](int U) {    // AREG: 4x f32x4 from u (k=i rows, contiguous in l)
        #pragma unroll
        for (int d = 0; d < 4; ++d)
            areg[d] = *(const f32x4*)&Ub[(size_t)(U * 32 + iq * 4 + d) * Ld + by * 256 + lq * 4];
    };
    auto writeA = [&](int U) {    // transpose 4i x 4l micro-block into padded A-region
        bf16* As = &lds[(U & 3) * SLOT];
        #pragma unroll
        for (int dl = 0; dl < 4; ++dl) {
            int r = lq * 4 + dl;
            bf16x4 wv = { (bf16)areg[0][dl], (bf16)areg[1][dl], (bf16)areg[2][dl], (bf16)areg[3][dl] };
            *(bf16x4*)&As[r * RS + iq * 4] = wv;
        }
    };
    auto readFrags = [&](int slot, bf16x8* avf, bf16x8* bvf) {
        const bf16* As = &lds[slot * SLOT];
        const bf16* Bs = &lds[slot * SLOT + ASZ];
        #pragma unroll
        for (int i = 0; i < 8; ++i) {
            int R = wm * 128 + i * 16 + fr;
            if (AREG) avf[i] = *(const bf16x8*)&As[R * RS + g * 8];
            else      avf[i] = *(const bf16x8*)&As[R * RS + (g ^ keyf(R)) * 8];
        }
        #pragma unroll
        for (int j = 0; j < 4; ++j) {
            int R = wn * 64 + j * 16 + fr;
            bvf[j] = *(const bf16x8*)&Bs[R * 32 + (g ^ keyf(R)) * 8];
        }
    };

    // ---- prologue ----
    if (AREG) { issueA(0); gldB(0); gldB(1); }
    else      { gldA(0); gldB(0); gldA(1); gldB(1); }

    // ---- hot loop: 16 units of BK=32 over K=512 ----
    for (int U = 0; U < 16; ++U) {
        if (U < 15) {
            if (AREG) asm volatile("s_waitcnt vmcnt(2)" ::: "memory");
            else      asm volatile("s_waitcnt vmcnt(4)" ::: "memory");
        } else {
            asm volatile("s_waitcnt vmcnt(0)" ::: "memory");
        }
        __builtin_amdgcn_sched_barrier(0);
        if (AREG) {
            writeA(U);
            asm volatile("s_waitcnt lgkmcnt(0)" ::: "memory");
            __builtin_amdgcn_sched_barrier(0);
        }
        __builtin_amdgcn_s_barrier();
        __builtin_amdgcn_sched_barrier(0);
        if (AREG && U + 1 < 16) {
            issueA(U + 1);                      // issue next areg loads early
            __builtin_amdgcn_sched_barrier(0);  // pin before gldB so vmcnt(2) count holds
        }
        bf16x8 av[8], bv[4];
        readFrags(U & 3, av, bv);
        if (!AREG && U + 2 < 16) gldA(U + 2);
        if (U + 2 < 16) gldB(U + 2);
        __builtin_amdgcn_s_setprio(1);
        #pragma unroll
        for (int i = 0; i < 8; ++i)
            #pragma unroll
            for (int j = 0; j < 4; ++j)
                acc[i][j] = __builtin_amdgcn_mfma_f32_16x16x32_bf16(av[i], bv[j], acc[i][j], 0, 0, 0);
        __builtin_amdgcn_s_setprio(0);
    }

    // ---- cold pass (gemm_y, D != 0 only; correctness path, not perf) ----
    if (!AREG) {
        if (extra) {
            #pragma unroll 1
            for (int T = 0; T < 16; ++T) {
                int k0 = T * 32;
                __builtin_amdgcn_s_barrier();
                f32x4 r4[4];
                #pragma unroll
                for (int d = 0; d < 4; ++d)
                    r4[d] = *(const f32x4*)&Ub[(size_t)(k0 + iq * 4 + d) * Ld + bx * 256 + lq * 4];
                #pragma unroll
                for (int rb = 0; rb < 2; ++rb) {
                    int row = rb * 128 + (tid >> 2);
                    int cs = (tid & 3) ^ keyf(row);
                    GLD16(Dbf + (size_t)(by * 256 + row) * 512 + k0 + cs * 8,
                          (rb * 128 + w * 16) * 32);
                }
                asm volatile("s_waitcnt vmcnt(0)" ::: "memory");
                #pragma unroll
                for (int dl = 0; dl < 4; ++dl) {
                    int r = lq * 4 + dl;
                    bf16x4 wv = { (bf16)r4[0][dl], (bf16)r4[1][dl], (bf16)r4[2][dl], (bf16)r4[3][dl] };
                    int e = ((iq >> 1) ^ keyf(r)) * 8 + (iq & 1) * 4;
                    *(bf16x4*)&lds[ASZ + r * 32 + e] = wv;
                }
                asm volatile("s_waitcnt lgkmcnt(0)" ::: "memory");
                __builtin_amdgcn_s_barrier();
                bf16x8 av[8], bv[4];
                readFrags(0, av, bv);
                #pragma unroll
                for (int i = 0; i < 8; ++i)
                    #pragma unroll
                    for (int j = 0; j < 4; ++j)
                        acc[i][j] = __builtin_amdgcn_mfma_f32_16x16x32_bf16(av[i], bv[j], acc[i][j], 0, 0, 0);
            }
        }
    }

    int n0 = bx * 256 + wn * 64 + fr;
    int m0 = by * 256 + wm * 128 + g * 4;

    // ---- fused chunk-end scan (gemm_bu only): wave rows wm*128..+128 == chunk by*2+wm
    if (SCAN) {
        #pragma unroll
        for (int j = 0; j < 4; ++j) {
            float a = A_diag[n0 + j * 16];
            float a2 = a * a, a4 = a2 * a2, a8 = a4 * a4, a16 = a8 * a8;
            float S = 0.f;
            #pragma unroll
            for (int i = 0; i < 8; ++i) {
                f32x4 v = acc[i][j];
                float e = fmaf(fmaf(fmaf(v[0], a, v[1]), a, v[2]), a, v[3]);
                float e0 = __shfl(e, fr), e1 = __shfl(e, fr + 16);
                float e2 = __shfl(e, fr + 32), e3 = __shfl(e, fr + 48);
                float E = fmaf(fmaf(fmaf(e0, a4, e1), a4, e2), a4, e3);
                S = fmaf(S, a16, E);
            }
            if (g == 0)
                cePtr[((size_t)b * NCd + (by * 2 + wm)) * Sd + n0 + j * 16] = S;
        }
    }

    // ---- store: C/D layout col=lane&15, row=(lane>>4)*4+reg ----
    if (SCAN) {
        bf16* out = (bf16*)OutV + (size_t)b * oBS;
        #pragma unroll
        for (int i = 0; i < 8; ++i)
            #pragma unroll
            for (int j = 0; j < 4; ++j)
                #pragma unroll
                for (int q = 0; q < 4; ++q)
                    out[(size_t)(m0 + i * 16 + q) * ldOut + n0 + j * 16] = (bf16)acc[i][j][q];
    } else {
        float* out = (float*)OutV + (size_t)b * oBS;
        #pragma unroll
        for (int i = 0; i < 8; ++i)
            #pragma unroll
            for (int j = 0; j < 4; ++j)
                #pragma unroll
                for (int q = 0; q < 4; ++q)
                    out[(size_t)(m0 + i * 16 + q) * ldOut + n0 + j * 16] = acc[i][j][q];
    }
    #undef GLD16
}

// ---- scan pass: carry (redone per block from ce) + full in-place scan, bf16x2
__global__ __launch_bounds__(256) void pass_scan2(bf16* __restrict__ xbuf,
                                                  const float* __restrict__ A_diag,
                                                  const float* __restrict__ ce,
                                                  const float* __restrict__ h0) {
    int gI = blockIdx.x * 256 + threadIdx.x;
    int sp = gI & 255;
    int c = (gI >> 8) & (NCd - 1);
    int b = gI >> 12;
    int s = sp * 2;
    float a0 = A_diag[s], a1 = A_diag[s + 1];
    float acl0 = a0, acl1 = a1;
    #pragma unroll
    for (int i = 0; i < 7; ++i) { acl0 *= acl0; acl1 *= acl1; }   // a^128
    float x0 = h0[s], x1 = h0[s + 1];
    for (int cp = 0; cp < NCd; ++cp) {
        if (cp >= c) break;
        float2 e = *(const float2*)&ce[((size_t)b * NCd + cp) * Sd + s];
        x0 = fmaf(acl0, x0, e.x);
        x1 = fmaf(acl1, x1, e.y);
    }
    bf16* p = xbuf + ((size_t)b * Ld + (size_t)c * CLd) * Sd + s;
    #pragma unroll 4
    for (int j = 0; j < CLd; ++j) {
        bf16x2 v = *(const bf16x2*)&p[(size_t)j * Sd];
        x0 = fmaf(a0, x0, (float)v[0]);
        x1 = fmaf(a1, x1, (float)v[1]);
        bf16x2 o = { (bf16)x0, (bf16)x1 };
        *(bf16x2*)&p[(size_t)j * Sd] = o;
    }
}

extern "C" void kernel_launch(void* const* d_in, const int* in_sizes, int n_in,
                              void* d_out, int out_size, void* d_ws, size_t ws_size,
                              hipStream_t stream) {
    const float* u  = (const float*)d_in[0];
    const float* Au = (const float*)d_in[1];
    const float* Bm = (const float*)d_in[2];
    const float* Cm = (const float*)d_in[3];
    const float* Dm = (const float*)d_in[4];
    const float* h0 = (const float*)d_in[5];
    float* Y = (float*)d_out;

    char* ws = (char*)d_ws;
    bf16* xs = (bf16*)ws;                              // 32 MiB: Bu -> scanned xs (bf16)
    bf16* Bb = (bf16*)(ws + (32ull << 20));            // 512 KiB each
    bf16* Cb = Bb + 262144;
    bf16* Db = Cb + 262144;
    float* A_diag = (float*)(ws + (32ull << 20) + 3ull * 524288);   // 2 KiB
    float* ce     = A_diag + 512;                      // 16*16*512 f32 = 512 KiB
    int*   dfa    = (int*)(ce + (size_t)BZd * NCd * Sd);  // 256 ints, written every call

    prep_all<<<769, 256, 0, stream>>>(Bm, Cm, Dm, Au, Bb, Cb, Db, A_diag, dfa);

    // gemm_bu: M=l(2048) via by (NY=8), N=s(512) via bx (NX=2); A from u (reg-transpose), B=Bb
    gemm8p<1, 1><<<(Sd / 256) * (Ld / 256) * BZd, 512, 0, stream>>>(
        nullptr, 0, u, (size_t)INd * Ld, Bb, 0, nullptr,
        nullptr, A_diag, ce,
        (void*)xs, (size_t)Ld * Sd, Sd,
        Sd / 256, Ld / 256);

    pass_scan2<<<(BZd * NCd * (Sd / 2)) / 256, 256, 0, stream>>>(xs, A_diag, ce, h0);

    // gemm_y: M=o(512) via by (NY=2), N=l(2048) via bx (NX=8); A=Cb, B=xs; cold D pass iff D!=0
    gemm8p<0, 0><<<(Ld / 256) * (Od / 256) * BZd, 512, 0, stream>>>(
        Cb, 0, u, (size_t)INd * Ld, xs, (size_t)Ld * Sd, Db,
        dfa, A_diag, nullptr,
        (void*)Y, (size_t)Od * Ld, Ld,
        Ld / 256, Od / 256);
}